// Round 8
// baseline (1501.730 us; speedup 1.0000x reference)
//
#include <hip/hip_runtime.h>
#include <hip/hip_bf16.h>
#include <math.h>

// Problem constants
#define T 256
#define B 64
#define FEAT 256
#define HID 1024
#define NCLS 257
#define NBLK 256           // 1 block per 4 hidden columns
#define NTHR 256           // 4 waves = 4-way K split
#define NPH (T * 4)        // 1024 phases (t, g)
#define HSLOT 16384        // shorts per h slot: 128 rows x 16 b x 8
#define XSLOT 4096         // shorts per x slot: 32 rows x 16 b x 8

typedef __attribute__((ext_vector_type(8))) short short8v;   // 8 x bf16
typedef __attribute__((ext_vector_type(4))) float floatx4;   // MFMA acc

// Hamilton block component/sign tables
__device__ __constant__ int   d_comp[4][4] = {{0,1,2,3},{1,0,3,2},{2,3,0,1},{3,2,1,0}};
__device__ __constant__ float d_sign[4][4] = {{ 1.f, 1.f, 1.f, 1.f},
                                              {-1.f, 1.f,-1.f, 1.f},
                                              {-1.f, 1.f, 1.f,-1.f},
                                              {-1.f,-1.f, 1.f, 1.f}};

__device__ __forceinline__ ushort f2bf(float f) {
    union { float f; unsigned u; } v; v.f = f;
    unsigned r = v.u + 0x7FFF + ((v.u >> 16) & 1);   // RNE
    return (ushort)(r >> 16);
}

__device__ __forceinline__ float sigm(float v) { return 1.f / (1.f + __expf(-v)); }
__device__ __forceinline__ float tanh_fast(float v) { return 1.f - 2.f / (1.f + __expf(2.f * v)); }

// x (fp32 [T][B][FEAT]) -> grouped panels xp[t*4+g][FEAT/8][16][8] bf16
__global__ __launch_bounds__(256) void conv_xpanel(const float* __restrict__ x,
                                                   ushort* __restrict__ xp) {
    int i = blockIdx.x * 256 + threadIdx.x;   // over T*B*FEAT/4
    int k4 = i & 63, b = (i >> 6) & 63, t = i >> 12;
    int k = k4 * 4;
    int g = b >> 4, b16 = b & 15;
    float4 v = ((const float4*)x)[i];
    ushort4 o;
    o.x = f2bf(v.x); o.y = f2bf(v.y); o.z = f2bf(v.z); o.w = f2bf(v.w);
    *(ushort4*)(xp + (size_t)(t * 4 + g) * XSLOT + (k >> 3) * 128 + b16 * 8 + (k & 7)) = o;
}

// Frag-ordered bf16 weights (A = W^T): e = ((blk*40 + ks)*64 + lane)*8 + j
//   gate col c = lane&15 -> hl = c>>2, gg = c&3; hidden col n = blk*4+hl
//   k = ks*32 + (lane>>4)*8 + j   (k<1024: Wh rows, else Wx rows)
__global__ __launch_bounds__(256) void prep_wcf(const float* __restrict__ Wh,
                                                const float* __restrict__ Wx,
                                                ushort* __restrict__ wcf) {
    int e = blockIdx.x * 256 + threadIdx.x;   // < 256*40*512 = 5,242,880
    int j    = e & 7;
    int lane = (e >> 3) & 63;
    int r    = e >> 9;
    int ks   = r % 40;
    int blk  = r / 40;
    int c  = lane & 15;
    int hl = c >> 2, gg = c & 3;
    int n  = blk * 4 + hl;
    int qq = n >> 8, bc = n & 255;
    int k  = ks * 32 + ((lane >> 4) << 3) + j;
    float v;
    if (k < HID) {
        int p = k >> 8, a = k & 255;
        v = d_sign[p][qq] * Wh[((gg * 4 + d_comp[p][qq]) * 256 + a) * 256 + bc];
    } else {
        int kk = k - HID;
        int p = kk >> 6, a = kk & 63;
        v = d_sign[p][qq] * Wx[((gg * 4 + d_comp[p][qq]) * 64 + a) * 256 + bc];
    }
    wcf[e] = f2bf(v);
}

// Wo -> frag-ordered bf16, cols padded to 320
__global__ __launch_bounds__(256) void prep_wof(const float* __restrict__ Wo,
                                                ushort* __restrict__ wof) {
    int e = blockIdx.x * 256 + threadIdx.x;   // < 20*32*512 = 327,680
    int j    = e & 7;
    int lane = (e >> 3) & 63;
    int ks   = (e >> 9) & 31;
    int tile = e >> 14;
    int n = tile * 16 + (lane & 15);
    int k = ks * 32 + ((lane >> 4) << 3) + j;
    wof[e] = (n < NCLS) ? f2bf(Wo[k * NCLS + n]) : (ushort)0;
}

// zero the flag array (4 groups x 256 blocks)
__global__ __launch_bounds__(256) void init_flags(uint* __restrict__ flg) {
    int i = threadIdx.x;
    flg[i] = 0; flg[256 + i] = 0; flg[512 + i] = 0; flg[768 + i] = 0;
}

// Persistent kernel: 1024 phases p = t*4 + g over 4 independent batch-group
// chains. Block blk owns hidden cols blk*4..+3 (16 gate cols). 4 waves = kq
// K-split (10 ksteps each). Per phase: MFMA(p) || poll(p+1) || loads(p+1) ||
// flag-peek(p+2), then LDS reduce + gates by wave g.
__global__ __launch_bounds__(256) void qlstm_persist(
    const ushort* __restrict__ xp,    // x panels [NPH][XSLOT]
    const ushort* __restrict__ wcf,   // frag-ordered weights
    const float*  __restrict__ bx,    // [4][1024]
    ushort*       __restrict__ hpan,  // h panels [NPH+4][HSLOT]; slot p = h input of phase p
    uint*         __restrict__ flg)   // [4][256]
{
    __shared__ float pre[2][4][16][20];

    const int tid  = threadIdx.x;
    const int blk  = blockIdx.x;
    const int kq   = tid >> 6;        // wave = K quarter
    const int lane = tid & 63;
    const int ld_off = (lane >> 4) * 128 + (lane & 15) * 8;

    // ---- weights -> registers (10 frags = 40 VGPR), pinned ----
    const short8v* wsrc = (const short8v*)wcf + (size_t)blk * 40 * 64 + lane;
    short8v Ah[8], Axr[2];
    #pragma unroll
    for (int i = 0; i < 8; ++i) Ah[i] = wsrc[(kq * 8 + i) * 64];
    #pragma unroll
    for (int u = 0; u < 2; ++u) Axr[u] = wsrc[(32 + kq * 2 + u) * 64];
    #pragma unroll
    for (int i = 0; i < 8; ++i) asm volatile("" : "+v"(Ah[i]));
    #pragma unroll
    for (int u = 0; u < 2; ++u) asm volatile("" : "+v"(Axr[u]));

    // ---- gate identity (active when wave kq == g): (b_loc, hc) ----
    const int gb_loc = lane >> 2;
    const int ghc    = lane & 3;
    const int gn     = blk * 4 + ghc;
    const float bxf = bx[gn], bxi = bx[HID + gn];
    const float bxo = bx[2 * HID + gn], bxa = bx[3 * HID + gn];
    const int st_off = (blk >> 1) * 128 + gb_loc * 8 + (blk & 1) * 4 + ghc;
    float c_reg = 0.f;

    // ---- pipeline state ----
    short8v hb[8], xv[2];
    uint4 fcarry = make_uint4(~0u, ~0u, ~0u, ~0u);
    // prologue: x loads for phase 0
    {
        const ushort* xs = xp;   // slot 0
        #pragma unroll
        for (int u = 0; u < 2; ++u)
            xv[u] = *(const short8v*)(xs + (kq * 2 + u) * 512 + ld_off);
    }

    for (int t = 0; t < T; ++t) {
        #pragma unroll
        for (int g = 0; g < 4; ++g) {
            const int p = t * 4 + g;

            // 1. MFMAs for phase p
            floatx4 acc = {0.f, 0.f, 0.f, 0.f};
            acc = __builtin_amdgcn_mfma_f32_16x16x32_bf16(Axr[0], xv[0], acc, 0, 0, 0);
            acc = __builtin_amdgcn_mfma_f32_16x16x32_bf16(Axr[1], xv[1], acc, 0, 0, 0);
            if (t > 0) {
                #pragma unroll
                for (int i = 0; i < 8; ++i)
                    acc = __builtin_amdgcn_mfma_f32_16x16x32_bf16(Ah[i], hb[i], acc, 0, 0, 0);
            }

            const int p1 = p + 1;
            // 2. x loads for p+1 (always available)
            if (p1 < NPH) {
                const ushort* xs = xp + (size_t)p1 * XSLOT;
                #pragma unroll
                for (int u = 0; u < 2; ++u)
                    xv[u] = *(const short8v*)(xs + (kq * 2 + u) * 512 + ld_off);
            }

            // 3. flag check for p+1 (flags were peeked 2 phases ago)
            if (p1 < NPH && p1 >= 4) {
                const uint tgt = (uint)(p1 >> 2);
                const int g2 = p1 & 3;
                uint4 fu = fcarry;
                bool ok = fu.x >= tgt && fu.y >= tgt && fu.z >= tgt && fu.w >= tgt;
                while (!__all(ok)) {
                    __builtin_amdgcn_s_sleep(1);
                    fu.x = __hip_atomic_load(flg + g2 * NBLK + lane,       __ATOMIC_RELAXED, __HIP_MEMORY_SCOPE_AGENT);
                    fu.y = __hip_atomic_load(flg + g2 * NBLK + 64 + lane,  __ATOMIC_RELAXED, __HIP_MEMORY_SCOPE_AGENT);
                    fu.z = __hip_atomic_load(flg + g2 * NBLK + 128 + lane, __ATOMIC_RELAXED, __HIP_MEMORY_SCOPE_AGENT);
                    fu.w = __hip_atomic_load(flg + g2 * NBLK + 192 + lane, __ATOMIC_RELAXED, __HIP_MEMORY_SCOPE_AGENT);
                    ok = fu.x >= tgt && fu.y >= tgt && fu.z >= tgt && fu.w >= tgt;
                }
                __builtin_amdgcn_sched_barrier(0);
                // 4. h loads for p+1 (fresh slot -> L2 miss -> MALL, fresh)
                const ushort* hs = hpan + (size_t)p1 * HSLOT;
                #pragma unroll
                for (int i = 0; i < 8; ++i)
                    hb[i] = *(const short8v*)(hs + (kq * 8 + i) * 512 + ld_off);
            }

            // 5. flag peek for p+2
            {
                const int p2 = p + 2;
                if (p2 < NPH && p2 >= 4) {
                    const int g3 = p2 & 3;
                    fcarry.x = __hip_atomic_load(flg + g3 * NBLK + lane,       __ATOMIC_RELAXED, __HIP_MEMORY_SCOPE_AGENT);
                    fcarry.y = __hip_atomic_load(flg + g3 * NBLK + 64 + lane,  __ATOMIC_RELAXED, __HIP_MEMORY_SCOPE_AGENT);
                    fcarry.z = __hip_atomic_load(flg + g3 * NBLK + 128 + lane, __ATOMIC_RELAXED, __HIP_MEMORY_SCOPE_AGENT);
                    fcarry.w = __hip_atomic_load(flg + g3 * NBLK + 192 + lane, __ATOMIC_RELAXED, __HIP_MEMORY_SCOPE_AGENT);
                } else {
                    fcarry = make_uint4(~0u, ~0u, ~0u, ~0u);
                }
            }

            // 6. K-split reduce staging + sync
            {
                const int pb = lane & 15;
                const int pm = (lane >> 4) * 4;
                #pragma unroll
                for (int jj = 0; jj < 4; ++jj)
                    pre[g & 1][kq][pb][pm + jj] = acc[jj];
            }
            __syncthreads();

            // 7. gates: wave g only
            if (kq == g) {
                float4 s0 = *(const float4*)&pre[g & 1][0][gb_loc][ghc * 4];
                float4 s1 = *(const float4*)&pre[g & 1][1][gb_loc][ghc * 4];
                float4 s2 = *(const float4*)&pre[g & 1][2][gb_loc][ghc * 4];
                float4 s3 = *(const float4*)&pre[g & 1][3][gb_loc][ghc * 4];
                float pf = s0.x + s1.x + s2.x + s3.x + bxf;
                float pi = s0.y + s1.y + s2.y + s3.y + bxi;
                float po = s0.z + s1.z + s2.z + s3.z + bxo;
                float pa = s0.w + s1.w + s2.w + s3.w + bxa;
                float f  = sigm(pf), i_ = sigm(pi), o = sigm(po);
                c_reg = i_ * tanh_fast(pa) + f * c_reg;
                float h = o * tanh_fast(c_reg);
                uint hvu = f2bf(h);
                ushort* hp = hpan + (size_t)(p + 4) * HSLOT + st_off;
                asm volatile("global_store_short %0, %1, off sc0 sc1"
                             :: "v"(hp), "v"(hvu) : "memory");
                asm volatile("s_waitcnt vmcnt(0)" ::: "memory");
                if (lane == 0)
                    __hip_atomic_store(flg + g * NBLK + blk, (uint)(t + 1),
                                       __ATOMIC_RELAXED, __HIP_MEMORY_SCOPE_AGENT);
            }
        }
    }
}

// Output projection: block (tt, nt); wave = batch group g (m-tile).
// A-frags = h from panels, B = wof, K = HID = 32 ksteps.
__global__ __launch_bounds__(256) void outproj(const ushort* __restrict__ hpan,
                                               const ushort* __restrict__ wof,
                                               const float* __restrict__ bo,
                                               float* __restrict__ out) {
    const int tt   = blockIdx.x;          // 0..255
    const int nt   = blockIdx.y;          // 0..4
    const int tid  = threadIdx.x;
    const int g    = tid >> 6;
    const int lane = tid & 63;
    const ushort* abase = hpan + ((size_t)(tt + 1) * 4 + g) * HSLOT
                          + (lane >> 4) * 128 + (lane & 15) * 8;
    const short8v* wb = (const short8v*)wof;

    floatx4 ac[4] = {{0.f,0.f,0.f,0.f},{0.f,0.f,0.f,0.f},
                     {0.f,0.f,0.f,0.f},{0.f,0.f,0.f,0.f}};
    #pragma unroll 4
    for (int ks = 0; ks < 32; ++ks) {
        short8v av = *(const short8v*)(abase + ks * 512);
        #pragma unroll
        for (int ct = 0; ct < 4; ++ct)
            ac[ct] = __builtin_amdgcn_mfma_f32_16x16x32_bf16(
                av, wb[((nt * 4 + ct) * 32 + ks) * 64 + lane], ac[ct], 0, 0, 0);
    }
    const int orow = tt * 64 + g * 16 + (lane >> 4) * 4;
    #pragma unroll
    for (int ct = 0; ct < 4; ++ct) {
        int n = nt * 64 + ct * 16 + (lane & 15);
        if (n < NCLS) {
            float bias = bo[n];
            #pragma unroll
            for (int j = 0; j < 4; ++j)
                out[(size_t)(orow + j) * NCLS + n] = ac[ct][j] + bias;
        }
    }
}

extern "C" void kernel_launch(void* const* d_in, const int* in_sizes, int n_in,
                              void* d_out, int out_size, void* d_ws, size_t ws_size,
                              hipStream_t stream) {
    const float* x  = (const float*)d_in[0];   // [T,B,FEAT]
    const float* Wx = (const float*)d_in[1];   // [4,4,64,256]
    const float* bx = (const float*)d_in[2];   // [4,HID]
    const float* Wh = (const float*)d_in[3];   // [4,4,256,256]
    const float* Wo = (const float*)d_in[4];   // [HID,NCLS]
    const float* bo = (const float*)d_in[5];   // [NCLS]
    float* out = (float*)d_out;

    // Workspace layout (ushort units), ~53.2 MB total
    ushort* xp   = (ushort*)d_ws;                          // NPH*XSLOT   = 4,194,304
    ushort* wcf  = xp  + (size_t)NPH * XSLOT;              // 256*40*512  = 5,242,880
    ushort* wof  = wcf + (size_t)256 * 40 * 512;           // 327,680
    ushort* hpan = wof + 327680;                           // (NPH+4)*HSLOT = 16,842,752
    uint*   flg  = (uint*)(hpan + (size_t)(NPH + 4) * HSLOT);

    conv_xpanel<<<(T * B * FEAT / 4) / 256, 256, 0, stream>>>(x, xp);
    prep_wcf<<<(256 * 40 * 512) / 256, 256, 0, stream>>>(Wh, Wx, wcf);
    prep_wof<<<(20 * 32 * 512) / 256, 256, 0, stream>>>(Wo, wof);
    init_flags<<<1, 256, 0, stream>>>(flg);

    void* args[] = {(void*)&xp, (void*)&wcf, (void*)&bx, (void*)&hpan, (void*)&flg};
    hipLaunchCooperativeKernel((void*)qlstm_persist, dim3(NBLK), dim3(NTHR),
                               args, 0, stream);

    outproj<<<dim3(T, 5), 256, 0, stream>>>(hpan, wof, bo, out);
}

// Round 9
// 1107.617 us; speedup vs baseline: 1.3558x; 1.3558x over previous
//
#include <hip/hip_runtime.h>
#include <hip/hip_bf16.h>
#include <math.h>

// Problem constants
#define T 256
#define B 64
#define FEAT 256
#define HID 1024
#define NCLS 257
#define NCH 4              // independent batch chains (16 batches each)
#define NCG 64             // column-groups = blocks per chain (16 hid cols each)
#define NBLK 256
#define NTHR 512
#define HSLOT 16384        // shorts per (t,chain) h slot: 128 rows x 16 b x 8
#define XSLOT 4096         // shorts per (t,chain) x slot: 32 rows x 16 b x 8

typedef __attribute__((ext_vector_type(8))) short short8v;   // 8 x bf16
typedef __attribute__((ext_vector_type(4))) float floatx4;   // MFMA acc

// Hamilton block component/sign tables
__device__ __constant__ int   d_comp[4][4] = {{0,1,2,3},{1,0,3,2},{2,3,0,1},{3,2,1,0}};
__device__ __constant__ float d_sign[4][4] = {{ 1.f, 1.f, 1.f, 1.f},
                                              {-1.f, 1.f,-1.f, 1.f},
                                              {-1.f, 1.f, 1.f,-1.f},
                                              {-1.f,-1.f, 1.f, 1.f}};

__device__ __forceinline__ ushort f2bf(float f) {
    union { float f; unsigned u; } v; v.f = f;
    unsigned r = v.u + 0x7FFF + ((v.u >> 16) & 1);   // RNE
    return (ushort)(r >> 16);
}

__device__ __forceinline__ float sigm(float v) { return 1.f / (1.f + __expf(-v)); }
__device__ __forceinline__ float tanh_fast(float v) { return 1.f - 2.f / (1.f + __expf(2.f * v)); }

// x (fp32 [T][B][FEAT]) -> per-(t,chain) panels xp[t*4+c][FEAT/8][16][8] bf16
__global__ __launch_bounds__(256) void conv_xpanel(const float* __restrict__ x,
                                                   ushort* __restrict__ xp) {
    int i = blockIdx.x * 256 + threadIdx.x;   // over T*B*FEAT/4
    int k4 = i & 63, b = (i >> 6) & 63, t = i >> 12;
    int k = k4 * 4;
    int c = b >> 4, b16 = b & 15;
    float4 v = ((const float4*)x)[i];
    ushort4 o;
    o.x = f2bf(v.x); o.y = f2bf(v.y); o.z = f2bf(v.z); o.w = f2bf(v.w);
    *(ushort4*)(xp + (size_t)(t * 4 + c) * XSLOT + (k >> 3) * 128 + b16 * 8 + (k & 7)) = o;
}

// Frag-ordered bf16 weights (A = W^T), per (cg, mt):
// e = (((cg*4 + mt)*40 + ks)*64 + lane)*8 + j
//   gate col c = mt*16 + (lane&15) in [0,64); hl = c>>2, g = c&3;
//   hidden col n = cg*16 + hl; k = ks*32 + (lane>>4)*8 + j
__global__ __launch_bounds__(256) void prep_wcf(const float* __restrict__ Wh,
                                                const float* __restrict__ Wx,
                                                ushort* __restrict__ wcf) {
    int e = blockIdx.x * 256 + threadIdx.x;   // < 64*4*40*512 = 5,242,880
    int j    = e & 7;
    int lane = (e >> 3) & 63;
    int r    = e >> 9;
    int ks   = r % 40;
    int s    = r / 40;
    int mt   = s & 3;
    int cg   = s >> 2;
    int c  = mt * 16 + (lane & 15);
    int hl = c >> 2, g = c & 3;
    int n  = cg * 16 + hl;
    int qq = n >> 8, bc = n & 255;
    int k  = ks * 32 + ((lane >> 4) << 3) + j;
    float v;
    if (k < HID) {
        int p = k >> 8, a = k & 255;
        v = d_sign[p][qq] * Wh[((g * 4 + d_comp[p][qq]) * 256 + a) * 256 + bc];
    } else {
        int kk = k - HID;
        int p = kk >> 6, a = kk & 63;
        v = d_sign[p][qq] * Wx[((g * 4 + d_comp[p][qq]) * 64 + a) * 256 + bc];
    }
    wcf[e] = f2bf(v);
}

// Wo -> frag-ordered bf16, cols padded to 320
__global__ __launch_bounds__(256) void prep_wof(const float* __restrict__ Wo,
                                                ushort* __restrict__ wof) {
    int e = blockIdx.x * 256 + threadIdx.x;   // < 20*32*512 = 327,680
    int j    = e & 7;
    int lane = (e >> 3) & 63;
    int ks   = (e >> 9) & 31;
    int tile = e >> 14;
    int n = tile * 16 + (lane & 15);
    int k = ks * 32 + ((lane >> 4) << 3) + j;
    wof[e] = (n < NCLS) ? f2bf(Wo[k * NCLS + n]) : (ushort)0;
}

// zero h slots (t=0, all 4 chains) and the 256 flags
__global__ __launch_bounds__(256) void init_hf(ushort* __restrict__ hpan,
                                               uint* __restrict__ flg) {
    int i = blockIdx.x * 256 + threadIdx.x;   // 64 blocks -> 16384 threads
    ((ushort4*)hpan)[i] = make_ushort4(0, 0, 0, 0);   // 65536 shorts = slots 0..3
    if (blockIdx.x == 0) flg[threadIdx.x] = 0;
}

// Persistent kernel: 4 independent chains. Block blk -> (chain = blk&3,
// cg = blk>>2): 16 hidden cols (64 gate cols) x 16 batches. 8 waves:
// mt = w&3 (m-tile of 16 gate cols), kh = w>>2 (20 of 40 ksteps).
// A-frags pinned in VGPRs via asm-volatile loads (20/wave = 80 VGPR).
__global__ __launch_bounds__(512, 2) void qlstm_persist(
    const ushort* __restrict__ xp,    // x panels [T*4][XSLOT]
    const ushort* __restrict__ wcf,   // frag-ordered weights
    const float*  __restrict__ bx,    // [4][1024]
    ushort*       __restrict__ hpan,  // h panels [(T+1)*4][HSLOT]; slot t*4+c = input of step t
    uint*         __restrict__ flg)   // [4][64] per-block step flags
{
    __shared__ float pre[2][16][72];  // [kh][batch][gatecol(64), pad 72]

    const int tid  = threadIdx.x;
    const int blk  = blockIdx.x;
    const int ch   = blk & 3;
    const int cg   = blk >> 2;
    const int w    = tid >> 6;
    const int lane = tid & 63;
    const int mt   = w & 3;
    const int kh   = w >> 2;
    const int ld_off = (lane >> 4) * 128 + (lane & 15) * 8;

    // ---- one-time: A-frags via volatile loads (cannot be re-executed) ----
    const ushort* wbase = wcf + ((size_t)(cg * 4 + mt) * 40 + kh * 20) * 512 + lane * 8;
    short8v A[20];
    #pragma unroll
    for (int i = 0; i < 20; ++i) {
        const ushort* ap = wbase + i * 512;
        asm volatile("global_load_dwordx4 %0, %1, off" : "=v"(A[i]) : "v"(ap));
    }
    asm volatile("s_waitcnt vmcnt(0)" ::: "memory");
    __builtin_amdgcn_sched_barrier(0);

    // ---- gate identity (tid<256): (gb = batch-local, hl = hidden-local) ----
    const int gb = tid >> 4;
    const int hl = tid & 15;
    const int gn = cg * 16 + hl;
    float bxf = 0.f, bxi = 0.f, bxo = 0.f, bxa = 0.f;
    if (tid < 256) {
        bxf = bx[gn]; bxi = bx[HID + gn];
        bxo = bx[2 * HID + gn]; bxa = bx[3 * HID + gn];
    }
    float c_reg = 0.f;
    const int st_off = (cg * 2 + (hl >> 3)) * 128 + gb * 8 + (hl & 7);
    uint* myflags = flg + ch * 64;

    for (int t = 0; t < T; ++t) {
        const ushort* hs = hpan + (size_t)(t * NCH + ch) * HSLOT;
        const ushort* xs = xp   + (size_t)(t * NCH + ch) * XSLOT;

        short8v Bf[20];
        // x loads (kh=1 waves): issue BEFORE the poll so they fly during the wait
        if (kh == 1) {
            #pragma unroll
            for (int i = 12; i < 20; ++i) {
                const ushort* p = xs + (i - 12) * 512 + ld_off;
                asm volatile("global_load_dwordx4 %0, %1, off" : "=v"(Bf[i]) : "v"(p));
            }
        }

        // barrier: wave 0 polls this chain's 64 flags, others wait at sync
        if (t > 0) {
            if (w == 0) {
                const uint tgt = (uint)t;
                for (;;) {
                    uint f = __hip_atomic_load(myflags + lane, __ATOMIC_RELAXED,
                                               __HIP_MEMORY_SCOPE_AGENT);
                    if (__all(f >= tgt)) break;
                    __builtin_amdgcn_s_sleep(1);
                }
            }
            __syncthreads();
        }

        // h loads (fresh slot -> miss -> MALL; replay-stale lines are identical)
        if (kh == 0) {
            #pragma unroll
            for (int i = 0; i < 20; ++i) {
                const ushort* p = hs + i * 512 + ld_off;
                asm volatile("global_load_dwordx4 %0, %1, off" : "=v"(Bf[i]) : "v"(p));
            }
        } else {
            #pragma unroll
            for (int i = 0; i < 12; ++i) {
                const ushort* p = hs + (20 + i) * 512 + ld_off;
                asm volatile("global_load_dwordx4 %0, %1, off" : "=v"(Bf[i]) : "v"(p));
            }
        }
        asm volatile("s_waitcnt vmcnt(0)" ::: "memory");
        __builtin_amdgcn_sched_barrier(0);

        floatx4 a0 = {0.f,0.f,0.f,0.f}, a1 = {0.f,0.f,0.f,0.f};
        #pragma unroll
        for (int i = 0; i < 20; i += 2) {
            a0 = __builtin_amdgcn_mfma_f32_16x16x32_bf16(A[i],     Bf[i],     a0, 0, 0, 0);
            a1 = __builtin_amdgcn_mfma_f32_16x16x32_bf16(A[i + 1], Bf[i + 1], a1, 0, 0, 0);
        }
        floatx4 acc = a0 + a1;

        // D: n(batch) = lane&15, m = (lane>>4)*4 + jj -> contiguous gate cols
        {
            float4 v = make_float4(acc[0], acc[1], acc[2], acc[3]);
            *(float4*)&pre[kh][lane & 15][mt * 16 + (lane >> 4) * 4] = v;
        }
        __syncthreads();

        // gates: tid<256, one (batch, hidden col) each; c in register
        if (tid < 256) {
            float4 p0 = *(const float4*)&pre[0][gb][hl * 4];
            float4 p1 = *(const float4*)&pre[1][gb][hl * 4];
            float f  = sigm(p0.x + p1.x + bxf);
            float i_ = sigm(p0.y + p1.y + bxi);
            float o  = sigm(p0.z + p1.z + bxo);
            float a  = p0.w + p1.w + bxa;
            c_reg = i_ * tanh_fast(a) + f * c_reg;
            float h = o * tanh_fast(c_reg);
            uint hvu = f2bf(h);
            ushort* hp = hpan + (size_t)((t + 1) * NCH + ch) * HSLOT + st_off;
            asm volatile("global_store_short %0, %1, off sc0 sc1"
                         :: "v"(hp), "v"(hvu) : "memory");
            asm volatile("s_waitcnt vmcnt(0)" ::: "memory");
        }
        __syncthreads();   // all h stores of this block drained & visible

        if (tid == 0)
            __hip_atomic_store(myflags + cg, (uint)(t + 1),
                               __ATOMIC_RELAXED, __HIP_MEMORY_SCOPE_AGENT);
    }
}

// Output projection: block (tt, nt); wave = batch group g (chain).
// A-frags = h from panel slot (tt+1)*4+g, B = wof, K = HID = 32 ksteps.
__global__ __launch_bounds__(256) void outproj(const ushort* __restrict__ hpan,
                                               const ushort* __restrict__ wof,
                                               const float* __restrict__ bo,
                                               float* __restrict__ out) {
    const int tt   = blockIdx.x;          // 0..255
    const int nt   = blockIdx.y;          // 0..4
    const int tid  = threadIdx.x;
    const int g    = tid >> 6;
    const int lane = tid & 63;
    const ushort* abase = hpan + ((size_t)(tt + 1) * 4 + g) * HSLOT
                          + (lane >> 4) * 128 + (lane & 15) * 8;
    const short8v* wb = (const short8v*)wof;

    floatx4 ac[4] = {{0.f,0.f,0.f,0.f},{0.f,0.f,0.f,0.f},
                     {0.f,0.f,0.f,0.f},{0.f,0.f,0.f,0.f}};
    #pragma unroll 4
    for (int ks = 0; ks < 32; ++ks) {
        short8v av = *(const short8v*)(abase + ks * 512);
        #pragma unroll
        for (int ct = 0; ct < 4; ++ct)
            ac[ct] = __builtin_amdgcn_mfma_f32_16x16x32_bf16(
                av, wb[((nt * 4 + ct) * 32 + ks) * 64 + lane], ac[ct], 0, 0, 0);
    }
    const int orow = tt * 64 + g * 16 + (lane >> 4) * 4;
    #pragma unroll
    for (int ct = 0; ct < 4; ++ct) {
        int n = nt * 64 + ct * 16 + (lane & 15);
        if (n < NCLS) {
            float bias = bo[n];
            #pragma unroll
            for (int j = 0; j < 4; ++j)
                out[(size_t)(orow + j) * NCLS + n] = ac[ct][j] + bias;
        }
    }
}

extern "C" void kernel_launch(void* const* d_in, const int* in_sizes, int n_in,
                              void* d_out, int out_size, void* d_ws, size_t ws_size,
                              hipStream_t stream) {
    const float* x  = (const float*)d_in[0];   // [T,B,FEAT]
    const float* Wx = (const float*)d_in[1];   // [4,4,64,256]
    const float* bx = (const float*)d_in[2];   // [4,HID]
    const float* Wh = (const float*)d_in[3];   // [4,4,256,256]
    const float* Wo = (const float*)d_in[4];   // [HID,NCLS]
    const float* bo = (const float*)d_in[5];   // [NCLS]
    float* out = (float*)d_out;

    // Workspace layout (ushort units), ~53.2 MB total
    ushort* xp   = (ushort*)d_ws;                          // T*4*XSLOT  = 4,194,304
    ushort* wcf  = xp  + (size_t)T * 4 * XSLOT;            // 5,242,880
    ushort* wof  = wcf + (size_t)64 * 4 * 40 * 512;        // 327,680
    ushort* hpan = wof + 327680;                           // (T+1)*4*HSLOT = 16,842,752
    uint*   flg  = (uint*)(hpan + (size_t)(T + 1) * 4 * HSLOT);

    conv_xpanel<<<(T * B * FEAT / 4) / 256, 256, 0, stream>>>(x, xp);
    prep_wcf<<<(64 * 4 * 40 * 512) / 256, 256, 0, stream>>>(Wh, Wx, wcf);
    prep_wof<<<(20 * 32 * 512) / 256, 256, 0, stream>>>(Wo, wof);
    init_hf<<<64, 256, 0, stream>>>(hpan, flg);

    void* args[] = {(void*)&xp, (void*)&wcf, (void*)&bx, (void*)&hpan, (void*)&flg};
    hipLaunchCooperativeKernel((void*)qlstm_persist, dim3(NBLK), dim3(NTHR),
                               args, 0, stream);

    outproj<<<dim3(T, 5), 256, 0, stream>>>(hpan, wof, bo, out);
}